// Round 15
// baseline (117.261 us; speedup 1.0000x reference)
//
#include <hip/hip_runtime.h>

#define N_TOT 8192
#define BHALF 4096
#define D_DIM 512
#define BM 128
#define NTILE 64          // N_TOT / BM
#define NBLOCKS 2080      // NTILE*(NTILE+1)/2 upper-triangle tiles
#define BKQ 64            // K per chunk (fp8: 64 B rows)
#define NCHUNK 8          // D_DIM / BKQ
#define BUFS 4096         // shorts per buffer (128 rows x 64 B = 8 KB)
#define NBUF 2            // double buffer, single-barrier, 1-deep prefetch

// Q = e4m3(256 * z/||z||). corr[r] = ZSCALE/||Q_r|| (exact f32). Then
// acc*cr*cc = (2/ln2)*cos(Q_i,Q_j) exactly -> exp2() is exp(2*cos), and the
// pos LOGIT (2*cos) = corrected * ln2.
#define ZSCALE 1.69864368f      // sqrt(2/ln(2))
#define LN2F   0.69314718f
#define SCALE_Q 256.0f          // exact power of 2

typedef float f32x4 __attribute__((ext_vector_type(4)));
typedef long long i64;
typedef i64 i64x2 __attribute__((ext_vector_type(2)));   // 16B: one ds_read_b128

// ---- hand-rolled OCP e4m3fn converters ----
__device__ __forceinline__ unsigned int f2e4m3(float x) {
    union { float f; unsigned u; } v; v.f = x;
    unsigned a = v.u & 0x7fffffffu;
    unsigned s = (v.u >> 24) & 0x80u;
    unsigned m;
    if (a < 0x3C800000u) {                       // |x| < 2^-6 -> subnormal
        union { unsigned u; float f; } w; w.u = a;
        m = (unsigned)(w.f * 512.0f + 0.5f);
    } else {                                     // normal, RNE to 3 mantissa bits
        unsigned r = a + 0x7FFFFu + ((a >> 20) & 1u);
        unsigned e8 = (r >> 23) - 120u;
        m = (e8 << 3) | ((r >> 20) & 7u);
    }
    return s | m;
}
__device__ __forceinline__ float e4m32f(unsigned b) {
    unsigned e = (b >> 3) & 15u, m = b & 7u;
    float v;
    if (e) { union { unsigned u; float f; } w; w.u = ((e + 120u) << 23) | (m << 20); v = w.f; }
    else v = (float)m * 0x1p-9f;
    return (b & 0x80u) ? -v : v;
}

__device__ __forceinline__ float fast_exp2(float x) {
#if __has_builtin(__builtin_amdgcn_exp2f)
    return __builtin_amdgcn_exp2f(x);
#else
    return exp2f(x);
#endif
}

// Kernel 1: row L2-normalize [zjs; zis], quantize to e4m3 (x256), store
// per-row exact norm correction. Blocks 0..31 zero rowsum.
//
// K-INTERLEAVED PACKING (R13, verified): within each 64B chunk window, 8B
// unit g = 2*quad_slice + kk holds original k [64kc + 32kk + 8qs, +8) -> a
// lane's TWO MFMA fragments are one contiguous 16B pair, read by ONE
// ds_read_b128 (b64 reads had 4.26M measured conflict cycles, R12).
// Lane l covers original k [8l,8l+8) -> uint2 slot (l&~7)+2(l&3)+((l>>2)&1).
__global__ __launch_bounds__(256) void normalize_kernel(
    const float* __restrict__ zis, const float* __restrict__ zjs,
    unsigned char* __restrict__ zq, float* __restrict__ corr,
    float* __restrict__ rowsum)
{
    if (blockIdx.x < 32) rowsum[blockIdx.x * 256 + threadIdx.x] = 0.0f;
    int wave = threadIdx.x >> 6;
    int lane = threadIdx.x & 63;
    int row  = blockIdx.x * 4 + wave;
    const float* src = (row < BHALF) ? (zjs + (size_t)row * D_DIM)
                                     : (zis + (size_t)(row - BHALF) * D_DIM);
    const float4* src4 = (const float4*)src;
    float4 v0 = src4[lane * 2];
    float4 v1 = src4[lane * 2 + 1];
    float ss = v0.x*v0.x + v0.y*v0.y + v0.z*v0.z + v0.w*v0.w
             + v1.x*v1.x + v1.y*v1.y + v1.z*v1.z + v1.w*v1.w;
    #pragma unroll
    for (int off = 1; off < 64; off <<= 1) ss += __shfl_xor(ss, off);
    float scale = SCALE_Q / fmaxf(sqrtf(ss), 1e-8f);

    float vals[8] = {v0.x, v0.y, v0.z, v0.w, v1.x, v1.y, v1.z, v1.w};
    unsigned b[8]; float ssq = 0.0f;
    #pragma unroll
    for (int i = 0; i < 8; ++i) {
        b[i] = f2e4m3(vals[i] * scale);
        float d = e4m32f(b[i]);
        ssq += d * d;
    }
    #pragma unroll
    for (int off = 1; off < 64; off <<= 1) ssq += __shfl_xor(ssq, off);

    uint2 o;
    o.x = b[0] | (b[1] << 8) | (b[2] << 16) | (b[3] << 24);
    o.y = b[4] | (b[5] << 8) | (b[6] << 16) | (b[7] << 24);
    const int slot = (lane & ~7) + 2 * (lane & 3) + ((lane >> 2) & 1);
    ((uint2*)(zq + (size_t)row * D_DIM))[slot] = o;
    if (lane == 0) corr[row] = ZSCALE / fmaxf(sqrtf(ssq), 1e-8f);
}

// Kernel 2: upper-triangle 128x128 tiles of exp2(corr-scaled Q.Q^T).
//
// ROUND 15 — SINGLE-BARRIER + DOUBLE BUFFER: the untested cell of the
// {barriers} x {occupancy} matrix. R14 proved 1-barrier beats 2-barrier at
// NBUF=3 (3 blocks/CU); R6->R10 proved independent-block TLP is this
// kernel's strongest resource. NBUF=2 -> LDS 32 KB -> 4 blocks/CU, keeping
// the 1-barrier loop: per iter {vmcnt(0); barrier; STAGE(kc+1 -> buf^1);
// COMPUTE(kc, buf)}. Race screen (R14 induction, depth 1): no wave crosses
// barrier kc before all finish COMPUTE(kc-1), so STAGE's target (kc+1)&1 ==
// (kc-1)&1 has no live readers; each wave drains its own chunk-kc loads
// (vmcnt(0)) pre-barrier, so post-barrier the whole buffer is valid. The
// drain is covered by one full COMPUTE (~400+cy) vs ~200-300cy L2 latency.
// Chassis: fp8 b128-packed fragments (R13), XCD swizzle (R6). absmax 0.
__global__ __launch_bounds__(256) void ntxent_tri_kernel(
    const unsigned char* __restrict__ zq, const float* __restrict__ corr,
    float* __restrict__ rowsum, float* __restrict__ pos_ws)
{
    __shared__ unsigned short As[NBUF * BUFS];   // 16 KB (2 buffers)
    __shared__ unsigned short Bs[NBUF * BUFS];   // 16 KB
    // rsum/csum overlay onto As after the K-loop -> total LDS 32 KB.

    const int tid  = threadIdx.x;
    const int wave = tid >> 6;
    const int lane = tid & 63;
    const int cq   = lane & 15;
    const int quad = lane >> 4;
    const int wr   = wave >> 1;    // wave row 0..1
    const int wc   = wave & 1;     // wave col 0..1

    // XCD-chunked bijective remap (2080 = 8 * 260).
    const int swzbid = (blockIdx.x & 7) * (NBLOCKS / 8) + (blockIdx.x >> 3);

    // swzbid -> (I,J), J-group-major (8 J-panels/group), I-major in group.
    int g = 0, rem = swzbid;
    while (rem >= 64 * g + 36) { rem -= 64 * g + 36; ++g; }
    int I, J;
    if (rem < 64 * g) { I = rem >> 3; J = 8 * g + (rem & 7); }
    else {
        rem -= 64 * g;
        int ii = 0;
        while (rem >= 8 - ii) { rem -= 8 - ii; ++ii; }
        I = 8 * g + ii;
        J = I + rem;
    }
    const int rowbase = I * BM;
    const int colbase = J * BM;
    const bool diagblk = (I == J);
    const bool posblk  = (J == I + NTILE / 2);   // contains (i, i+BHALF) pairs

    // Staging: thread t, round rnd covers row r = rnd*64 + (t>>2), 16B pair
    // p = t&3; stored pair p holds global pair p ^ ((r>>1)&3).
    const int c16 = (tid & 3) ^ ((tid >> 3) & 3);
    const unsigned char* pA0 = zq + (size_t)(rowbase + (tid >> 2)) * D_DIM + c16 * 16;
    const unsigned char* pA1 = pA0 + (size_t)64 * D_DIM;
    const unsigned char* pB0 = zq + (size_t)(colbase + (tid >> 2)) * D_DIM + c16 * 16;
    const unsigned char* pB1 = pB0 + (size_t)64 * D_DIM;
    const int dst0 = tid * 8;            // shorts; round 0
    const int dst1 = 2048 + tid * 8;     // shorts; round 1

    // Fragment reads (ds_read_b128): row ra = wr*64+t*16+cq; global pair
    // quad lives at stored pair quad ^ ((ra>>1)&3) = quad ^ ((cq>>1)&3).
    const int po = (quad ^ ((cq >> 1) & 3)) * 8;   // shorts
    int aOffS[4], bOffS[4];
    #pragma unroll
    for (int t = 0; t < 4; ++t) {
        aOffS[t] = (wr * 64 + t * 16 + cq) * 32 + po;
        bOffS[t] = (wc * 64 + t * 16 + cq) * 32 + po;
    }

    f32x4 acc[4][4];
    #pragma unroll
    for (int a = 0; a < 4; ++a)
        #pragma unroll
        for (int b = 0; b < 4; ++b)
            acc[a][b] = (f32x4){0.f, 0.f, 0.f, 0.f};

#define STAGE(buf) do {                                                          \
    const int dbase = (buf) * BUFS;                                              \
    __builtin_amdgcn_global_load_lds(                                            \
        (const __attribute__((address_space(1))) unsigned int*)pA0,              \
        (__attribute__((address_space(3))) unsigned int*)&As[dbase + dst0],      \
        16, 0, 0);                                                               \
    __builtin_amdgcn_global_load_lds(                                            \
        (const __attribute__((address_space(1))) unsigned int*)pA1,              \
        (__attribute__((address_space(3))) unsigned int*)&As[dbase + dst1],      \
        16, 0, 0);                                                               \
    __builtin_amdgcn_global_load_lds(                                            \
        (const __attribute__((address_space(1))) unsigned int*)pB0,              \
        (__attribute__((address_space(3))) unsigned int*)&Bs[dbase + dst0],      \
        16, 0, 0);                                                               \
    __builtin_amdgcn_global_load_lds(                                            \
        (const __attribute__((address_space(1))) unsigned int*)pB1,              \
        (__attribute__((address_space(3))) unsigned int*)&Bs[dbase + dst1],      \
        16, 0, 0);                                                               \
    pA0 += BKQ; pA1 += BKQ; pB0 += BKQ; pB1 += BKQ;                              \
} while (0)

#define COMPUTE(buf) do {                                                        \
    const int cbase = (buf) * BUFS;                                              \
    i64x2 af[4], bf[4];                                                          \
    _Pragma("unroll")                                                            \
    for (int t = 0; t < 4; ++t) {                                                \
        af[t] = *(const i64x2*)&As[cbase + aOffS[t]];                            \
        bf[t] = *(const i64x2*)&Bs[cbase + bOffS[t]];                            \
    }                                                                            \
    _Pragma("unroll")                                                            \
    for (int ar = 0; ar < 4; ++ar)                                               \
        _Pragma("unroll")                                                        \
        for (int bc = 0; bc < 4; ++bc)                                           \
            acc[ar][bc] = __builtin_amdgcn_mfma_f32_16x16x32_fp8_fp8(            \
                af[ar].x, bf[bc].x, acc[ar][bc], 0, 0, 0);                       \
    _Pragma("unroll")                                                            \
    for (int ar = 0; ar < 4; ++ar)                                               \
        _Pragma("unroll")                                                        \
        for (int bc = 0; bc < 4; ++bc)                                           \
            acc[ar][bc] = __builtin_amdgcn_mfma_f32_16x16x32_fp8_fp8(            \
                af[ar].y, bf[bc].y, acc[ar][bc], 0, 0, 0);                       \
} while (0)

    // Prologue: stage chunk 0 into buffer 0 (4 loads in flight).
    STAGE(0);
    #pragma unroll
    for (int kc = 0; kc < NCHUNK; ++kc) {
        asm volatile("s_waitcnt vmcnt(0)" ::: "memory");  // my chunk-kc loads landed
        __builtin_amdgcn_s_barrier();        // all landed + all done COMPUTE(kc-1)
        __builtin_amdgcn_sched_barrier(0);   // no hoisting across
        if (kc + 1 < NCHUNK) STAGE((kc + 1) & 1);  // overwrite kc-1's read buf
        COMPUTE(kc & 1);
    }

    // ---- exact norm correction: acc *= cr*cc -> (2/ln2)*cos(Q_i,Q_j) ----
    float cr[4][4], cc[4];
    #pragma unroll
    for (int ar = 0; ar < 4; ++ar)
        #pragma unroll
        for (int reg = 0; reg < 4; ++reg)
            cr[ar][reg] = corr[rowbase + wr * 64 + ar * 16 + quad * 4 + reg];
    #pragma unroll
    for (int bc = 0; bc < 4; ++bc)
        cc[bc] = corr[colbase + wc * 64 + bc * 16 + cq];
    #pragma unroll
    for (int ar = 0; ar < 4; ++ar)
        #pragma unroll
        for (int bc = 0; bc < 4; ++bc)
            #pragma unroll
            for (int reg = 0; reg < 4; ++reg)
                acc[ar][bc][reg] *= cr[ar][reg] * cc[bc];

    // pos extraction AFTER corr, BEFORE exp: logit (2*cos) = acc * ln2.
    if (posblk && wc == wr) {
        #pragma unroll
        for (int ar = 0; ar < 4; ++ar)
            #pragma unroll
            for (int reg = 0; reg < 4; ++reg)
                if (cq == quad * 4 + reg) {
                    int gr = rowbase + wr * 64 + ar * 16 + quad * 4 + reg;
                    pos_ws[gr] = acc[ar][ar][reg] * LN2F;
                }
    }

    // exp2 is the native op: one v_exp_f32 per element.
    #pragma unroll
    for (int ar = 0; ar < 4; ++ar)
        #pragma unroll
        for (int bc = 0; bc < 4; ++bc)
            #pragma unroll
            for (int reg = 0; reg < 4; ++reg)
                acc[ar][bc][reg] = fast_exp2(acc[ar][bc][reg]);
    if (diagblk && wr == wc) {
        #pragma unroll
        for (int ar = 0; ar < 4; ++ar)
            #pragma unroll
            for (int reg = 0; reg < 4; ++reg)
                if (cq == quad * 4 + reg) acc[ar][ar][reg] = 0.0f;
    }

    // ---- LDS overlay: rsum/csum reuse As (K-loop readers all done) ----
    float* rsum_lds = (float*)As;         // floats [0..127]
    float* csum_lds = rsum_lds + BM;      // floats [128..255]
    __syncthreads();                       // all waves past their LDS reads
    ((float*)As)[tid] = 0.0f;              // 256 floats = rsum + csum
    __syncthreads();

    // Row sums: sum over 16 cols (bc in-register, cq via shuffle).
    #pragma unroll
    for (int ar = 0; ar < 4; ++ar) {
        float rs[4];
        #pragma unroll
        for (int reg = 0; reg < 4; ++reg) {
            float v = acc[ar][0][reg] + acc[ar][1][reg] + acc[ar][2][reg] + acc[ar][3][reg];
            v += __shfl_xor(v, 1); v += __shfl_xor(v, 2);
            v += __shfl_xor(v, 4); v += __shfl_xor(v, 8);
            rs[reg] = v;
        }
        if (cq == 0) {
            #pragma unroll
            for (int reg = 0; reg < 4; ++reg)
                atomicAdd(&rsum_lds[wr * 64 + ar * 16 + quad * 4 + reg], rs[reg]);
        }
    }

    // Col sums (symmetry): only for off-diagonal blocks.
    if (!diagblk) {
        #pragma unroll
        for (int bc = 0; bc < 4; ++bc) {
            float cs = 0.0f;
            #pragma unroll
            for (int ar = 0; ar < 4; ++ar)
                #pragma unroll
                for (int reg = 0; reg < 4; ++reg)
                    cs += acc[ar][bc][reg];
            cs += __shfl_xor(cs, 16); cs += __shfl_xor(cs, 32);
            if (quad == 0) atomicAdd(&csum_lds[wc * 64 + bc * 16 + cq], cs);
        }
    }

    __syncthreads();
    if (tid < BM) atomicAdd(&rowsum[rowbase + tid], rsum_lds[tid]);
    else if (!diagblk) atomicAdd(&rowsum[colbase + tid - BM], csum_lds[tid - BM]);
#undef STAGE
#undef COMPUTE
}

// Kernel 3: single block, 1024 threads (16 waves; L2-latency-bound).
// mean_r( log(rowsum[r]) - pos[r & (BHALF-1)] ).
__global__ __launch_bounds__(1024) void finalize_kernel(
    const float* __restrict__ rowsum, const float* __restrict__ pos_ws,
    float* __restrict__ out)
{
    __shared__ float red[16];
    float s = 0.0f;
    for (int r = threadIdx.x; r < N_TOT; r += 1024)
        s += __logf(rowsum[r]) - pos_ws[r & (BHALF - 1)];
    #pragma unroll
    for (int off = 1; off < 64; off <<= 1) s += __shfl_xor(s, off);
    int wave = threadIdx.x >> 6, lane = threadIdx.x & 63;
    if (lane == 0) red[wave] = s;
    __syncthreads();
    if (threadIdx.x < 64) {
        float v = (threadIdx.x < 16) ? red[threadIdx.x] : 0.0f;
        #pragma unroll
        for (int off = 1; off < 16; off <<= 1) v += __shfl_xor(v, off);
        if (threadIdx.x == 0) out[0] = v * (1.0f / N_TOT);
    }
}

extern "C" void kernel_launch(void* const* d_in, const int* in_sizes, int n_in,
                              void* d_out, int out_size, void* d_ws, size_t ws_size,
                              hipStream_t stream) {
    const float* zis = (const float*)d_in[0];
    const float* zjs = (const float*)d_in[1];
    float* rowsum = (float*)d_ws;                                   // 32 KB
    float* pos_ws = rowsum + N_TOT;                                 // 16 KB
    float* corr   = pos_ws + BHALF;                                 // 32 KB
    unsigned char* zq = (unsigned char*)(corr + N_TOT);             // 4 MB, 16B-aligned
    float* out = (float*)d_out;

    normalize_kernel<<<N_TOT / 4, 256, 0, stream>>>(zis, zjs, zq, corr, rowsum);
    ntxent_tri_kernel<<<NBLOCKS, 256, 0, stream>>>(zq, corr, rowsum, pos_ws);
    finalize_kernel<<<1, 1024, 0, stream>>>(rowsum, pos_ws, out);
}

// Round 16
// 110.008 us; speedup vs baseline: 1.0659x; 1.0659x over previous
//
#include <hip/hip_runtime.h>

#define N_TOT 8192
#define BHALF 4096
#define D_DIM 512
#define BM 128
#define NTILE 64          // N_TOT / BM
#define NBLOCKS 2080      // NTILE*(NTILE+1)/2 upper-triangle tiles
#define BKQ 64            // K per chunk (fp8: 64 B rows)
#define NCHUNK 8          // D_DIM / BKQ
#define BUFS 4096         // shorts per buffer (128 rows x 64 B = 8 KB)
#define NBUF 3            // triple buffer: 2-deep prefetch (R11/R14-proven)

// Q = e4m3(256 * z/||z||). corr[r] = ZSCALE/||Q_r|| (exact f32). Then
// acc*cr*cc = (2/ln2)*cos(Q_i,Q_j) exactly -> exp2() is exp(2*cos), and the
// pos LOGIT (2*cos) = corrected * ln2.
#define ZSCALE 1.69864368f      // sqrt(2/ln(2))
#define LN2F   0.69314718f
#define SCALE_Q 256.0f          // exact power of 2

typedef float f32x4 __attribute__((ext_vector_type(4)));
typedef long long i64;
typedef i64 i64x2 __attribute__((ext_vector_type(2)));   // 16B: one ds_read_b128

// ---- hand-rolled OCP e4m3fn converters ----
__device__ __forceinline__ unsigned int f2e4m3(float x) {
    union { float f; unsigned u; } v; v.f = x;
    unsigned a = v.u & 0x7fffffffu;
    unsigned s = (v.u >> 24) & 0x80u;
    unsigned m;
    if (a < 0x3C800000u) {                       // |x| < 2^-6 -> subnormal
        union { unsigned u; float f; } w; w.u = a;
        m = (unsigned)(w.f * 512.0f + 0.5f);
    } else {                                     // normal, RNE to 3 mantissa bits
        unsigned r = a + 0x7FFFFu + ((a >> 20) & 1u);
        unsigned e8 = (r >> 23) - 120u;
        m = (e8 << 3) | ((r >> 20) & 7u);
    }
    return s | m;
}
__device__ __forceinline__ float e4m32f(unsigned b) {
    unsigned e = (b >> 3) & 15u, m = b & 7u;
    float v;
    if (e) { union { unsigned u; float f; } w; w.u = ((e + 120u) << 23) | (m << 20); v = w.f; }
    else v = (float)m * 0x1p-9f;
    return (b & 0x80u) ? -v : v;
}

__device__ __forceinline__ float fast_exp2(float x) {
#if __has_builtin(__builtin_amdgcn_exp2f)
    return __builtin_amdgcn_exp2f(x);
#else
    return exp2f(x);
#endif
}

// Kernel 1: row L2-normalize [zjs; zis], quantize to e4m3 (x256), store
// per-row exact norm correction. Blocks 0..31 zero rowsum.
//
// K-INTERLEAVED PACKING (R13, verified -7.5us): within each 64B chunk
// window, 8B unit g = 2*quad_slice + kk holds original k
// [64kc + 32kk + 8qs, +8) -> a lane's TWO MFMA fragments are one contiguous
// 16B pair, read by ONE ds_read_b128 (b64 had 4.26M conflict cycles, R12).
// Lane l covers original k [8l,8l+8) -> uint2 slot (l&~7)+2(l&3)+((l>>2)&1).
__global__ __launch_bounds__(256) void normalize_kernel(
    const float* __restrict__ zis, const float* __restrict__ zjs,
    unsigned char* __restrict__ zq, float* __restrict__ corr,
    float* __restrict__ rowsum)
{
    if (blockIdx.x < 32) rowsum[blockIdx.x * 256 + threadIdx.x] = 0.0f;
    int wave = threadIdx.x >> 6;
    int lane = threadIdx.x & 63;
    int row  = blockIdx.x * 4 + wave;
    const float* src = (row < BHALF) ? (zjs + (size_t)row * D_DIM)
                                     : (zis + (size_t)(row - BHALF) * D_DIM);
    const float4* src4 = (const float4*)src;
    float4 v0 = src4[lane * 2];
    float4 v1 = src4[lane * 2 + 1];
    float ss = v0.x*v0.x + v0.y*v0.y + v0.z*v0.z + v0.w*v0.w
             + v1.x*v1.x + v1.y*v1.y + v1.z*v1.z + v1.w*v1.w;
    #pragma unroll
    for (int off = 1; off < 64; off <<= 1) ss += __shfl_xor(ss, off);
    float scale = SCALE_Q / fmaxf(sqrtf(ss), 1e-8f);

    float vals[8] = {v0.x, v0.y, v0.z, v0.w, v1.x, v1.y, v1.z, v1.w};
    unsigned b[8]; float ssq = 0.0f;
    #pragma unroll
    for (int i = 0; i < 8; ++i) {
        b[i] = f2e4m3(vals[i] * scale);
        float d = e4m32f(b[i]);
        ssq += d * d;
    }
    #pragma unroll
    for (int off = 1; off < 64; off <<= 1) ssq += __shfl_xor(ssq, off);

    uint2 o;
    o.x = b[0] | (b[1] << 8) | (b[2] << 16) | (b[3] << 24);
    o.y = b[4] | (b[5] << 8) | (b[6] << 16) | (b[7] << 24);
    const int slot = (lane & ~7) + 2 * (lane & 3) + ((lane >> 2) & 1);
    ((uint2*)(zq + (size_t)row * D_DIM))[slot] = o;
    if (lane == 0) corr[row] = ZSCALE / fmaxf(sqrtf(ssq), 1e-8f);
}

// Kernel 2: upper-triangle 128x128 tiles of exp2(corr-scaled Q.Q^T).
//
// FINAL STRUCTURE (R14, verified best: total 110.0us, tri 45.7us, absmax 0).
// Single-barrier K-loop with counted vmcnt + triple buffer (2-deep
// prefetch): per iter kc {vmcnt(4) (own chunk-kc loads landed); barrier
// (also certifies all finished COMPUTE(kc-1)); STAGE(kc+2) into (kc-1)'s
// read buffer; COMPUTE(kc)}. vmcnt never drains to 0 mid-loop.
// Structure matrix closed: 2bar/2buf 50.8 (R12) | 2bar/3buf 53.9 (R11) |
// 1bar/3buf 45.7 (R14 WINNER) | 1bar/2buf 52.0 (R15 -- vmcnt(0) drain
// parks waves; occupancy gain never materializes).
// Chassis: fp8 b128-packed fragments (R13), XCD-chunked swizzle (R6,
// FETCH 72.8->10 MB), exp2/ZSCALE folding (R2), exact norm correction.
__global__ __launch_bounds__(256) void ntxent_tri_kernel(
    const unsigned char* __restrict__ zq, const float* __restrict__ corr,
    float* __restrict__ rowsum, float* __restrict__ pos_ws)
{
    __shared__ unsigned short As[NBUF * BUFS];   // 24 KB (3 buffers)
    __shared__ unsigned short Bs[NBUF * BUFS];   // 24 KB
    // rsum/csum overlay onto As after the K-loop -> total LDS 48 KB.

    const int tid  = threadIdx.x;
    const int wave = tid >> 6;
    const int lane = tid & 63;
    const int cq   = lane & 15;
    const int quad = lane >> 4;
    const int wr   = wave >> 1;    // wave row 0..1
    const int wc   = wave & 1;     // wave col 0..1

    // XCD-chunked bijective remap (2080 = 8 * 260).
    const int swzbid = (blockIdx.x & 7) * (NBLOCKS / 8) + (blockIdx.x >> 3);

    // swzbid -> (I,J), J-group-major (8 J-panels/group), I-major in group.
    int g = 0, rem = swzbid;
    while (rem >= 64 * g + 36) { rem -= 64 * g + 36; ++g; }
    int I, J;
    if (rem < 64 * g) { I = rem >> 3; J = 8 * g + (rem & 7); }
    else {
        rem -= 64 * g;
        int ii = 0;
        while (rem >= 8 - ii) { rem -= 8 - ii; ++ii; }
        I = 8 * g + ii;
        J = I + rem;
    }
    const int rowbase = I * BM;
    const int colbase = J * BM;
    const bool diagblk = (I == J);
    const bool posblk  = (J == I + NTILE / 2);   // contains (i, i+BHALF) pairs

    // Staging: thread t, round rnd covers row r = rnd*64 + (t>>2), 16B pair
    // p = t&3; stored pair p holds global pair p ^ ((r>>1)&3).
    const int c16 = (tid & 3) ^ ((tid >> 3) & 3);
    const unsigned char* pA0 = zq + (size_t)(rowbase + (tid >> 2)) * D_DIM + c16 * 16;
    const unsigned char* pA1 = pA0 + (size_t)64 * D_DIM;
    const unsigned char* pB0 = zq + (size_t)(colbase + (tid >> 2)) * D_DIM + c16 * 16;
    const unsigned char* pB1 = pB0 + (size_t)64 * D_DIM;
    const int dst0 = tid * 8;            // shorts; round 0
    const int dst1 = 2048 + tid * 8;     // shorts; round 1

    // Fragment reads (ds_read_b128): row ra = wr*64+t*16+cq; global pair
    // quad lives at stored pair quad ^ ((ra>>1)&3) = quad ^ ((cq>>1)&3).
    const int po = (quad ^ ((cq >> 1) & 3)) * 8;   // shorts
    int aOffS[4], bOffS[4];
    #pragma unroll
    for (int t = 0; t < 4; ++t) {
        aOffS[t] = (wr * 64 + t * 16 + cq) * 32 + po;
        bOffS[t] = (wc * 64 + t * 16 + cq) * 32 + po;
    }

    f32x4 acc[4][4];
    #pragma unroll
    for (int a = 0; a < 4; ++a)
        #pragma unroll
        for (int b = 0; b < 4; ++b)
            acc[a][b] = (f32x4){0.f, 0.f, 0.f, 0.f};

#define STAGE(buf) do {                                                          \
    const int dbase = (buf) * BUFS;                                              \
    __builtin_amdgcn_global_load_lds(                                            \
        (const __attribute__((address_space(1))) unsigned int*)pA0,              \
        (__attribute__((address_space(3))) unsigned int*)&As[dbase + dst0],      \
        16, 0, 0);                                                               \
    __builtin_amdgcn_global_load_lds(                                            \
        (const __attribute__((address_space(1))) unsigned int*)pA1,              \
        (__attribute__((address_space(3))) unsigned int*)&As[dbase + dst1],      \
        16, 0, 0);                                                               \
    __builtin_amdgcn_global_load_lds(                                            \
        (const __attribute__((address_space(1))) unsigned int*)pB0,              \
        (__attribute__((address_space(3))) unsigned int*)&Bs[dbase + dst0],      \
        16, 0, 0);                                                               \
    __builtin_amdgcn_global_load_lds(                                            \
        (const __attribute__((address_space(1))) unsigned int*)pB1,              \
        (__attribute__((address_space(3))) unsigned int*)&Bs[dbase + dst1],      \
        16, 0, 0);                                                               \
    pA0 += BKQ; pA1 += BKQ; pB0 += BKQ; pB1 += BKQ;                              \
} while (0)

#define COMPUTE(buf) do {                                                        \
    const int cbase = (buf) * BUFS;                                              \
    i64x2 af[4], bf[4];                                                          \
    _Pragma("unroll")                                                            \
    for (int t = 0; t < 4; ++t) {                                                \
        af[t] = *(const i64x2*)&As[cbase + aOffS[t]];                            \
        bf[t] = *(const i64x2*)&Bs[cbase + bOffS[t]];                            \
    }                                                                            \
    _Pragma("unroll")                                                            \
    for (int ar = 0; ar < 4; ++ar)                                               \
        _Pragma("unroll")                                                        \
        for (int bc = 0; bc < 4; ++bc)                                           \
            acc[ar][bc] = __builtin_amdgcn_mfma_f32_16x16x32_fp8_fp8(            \
                af[ar].x, bf[bc].x, acc[ar][bc], 0, 0, 0);                       \
    _Pragma("unroll")                                                            \
    for (int ar = 0; ar < 4; ++ar)                                               \
        _Pragma("unroll")                                                        \
        for (int bc = 0; bc < 4; ++bc)                                           \
            acc[ar][bc] = __builtin_amdgcn_mfma_f32_16x16x32_fp8_fp8(            \
                af[ar].y, bf[bc].y, acc[ar][bc], 0, 0, 0);                       \
} while (0)

    // Prologue: stage chunks 0,1 into buffers 0,1 (8 loads in flight).
    STAGE(0);
    STAGE(1);
    #pragma unroll
    for (int kc = 0; kc < NCHUNK; ++kc) {
        if (kc < NCHUNK - 1)
            asm volatile("s_waitcnt vmcnt(4)" ::: "memory");   // my chunk-kc loads landed
        else
            asm volatile("s_waitcnt vmcnt(0)" ::: "memory");
        __builtin_amdgcn_s_barrier();        // all landed + all done COMPUTE(kc-1)
        __builtin_amdgcn_sched_barrier(0);   // no hoisting across
        if (kc + 2 < NCHUNK) STAGE((kc + 2) % NBUF);  // overwrite kc-1's read buf
        COMPUTE(kc % NBUF);
    }

    // ---- exact norm correction: acc *= cr*cc -> (2/ln2)*cos(Q_i,Q_j) ----
    float cr[4][4], cc[4];
    #pragma unroll
    for (int ar = 0; ar < 4; ++ar)
        #pragma unroll
        for (int reg = 0; reg < 4; ++reg)
            cr[ar][reg] = corr[rowbase + wr * 64 + ar * 16 + quad * 4 + reg];
    #pragma unroll
    for (int bc = 0; bc < 4; ++bc)
        cc[bc] = corr[colbase + wc * 64 + bc * 16 + cq];
    #pragma unroll
    for (int ar = 0; ar < 4; ++ar)
        #pragma unroll
        for (int bc = 0; bc < 4; ++bc)
            #pragma unroll
            for (int reg = 0; reg < 4; ++reg)
                acc[ar][bc][reg] *= cr[ar][reg] * cc[bc];

    // pos extraction AFTER corr, BEFORE exp: logit (2*cos) = acc * ln2.
    if (posblk && wc == wr) {
        #pragma unroll
        for (int ar = 0; ar < 4; ++ar)
            #pragma unroll
            for (int reg = 0; reg < 4; ++reg)
                if (cq == quad * 4 + reg) {
                    int gr = rowbase + wr * 64 + ar * 16 + quad * 4 + reg;
                    pos_ws[gr] = acc[ar][ar][reg] * LN2F;
                }
    }

    // exp2 is the native op: one v_exp_f32 per element.
    #pragma unroll
    for (int ar = 0; ar < 4; ++ar)
        #pragma unroll
        for (int bc = 0; bc < 4; ++bc)
            #pragma unroll
            for (int reg = 0; reg < 4; ++reg)
                acc[ar][bc][reg] = fast_exp2(acc[ar][bc][reg]);
    if (diagblk && wr == wc) {
        #pragma unroll
        for (int ar = 0; ar < 4; ++ar)
            #pragma unroll
            for (int reg = 0; reg < 4; ++reg)
                if (cq == quad * 4 + reg) acc[ar][ar][reg] = 0.0f;
    }

    // ---- LDS overlay: rsum/csum reuse As (K-loop readers all done) ----
    float* rsum_lds = (float*)As;         // floats [0..127]
    float* csum_lds = rsum_lds + BM;      // floats [128..255]
    __syncthreads();                       // all waves past their LDS reads
    ((float*)As)[tid] = 0.0f;              // 256 floats = rsum + csum
    __syncthreads();

    // Row sums: sum over 16 cols (bc in-register, cq via shuffle).
    #pragma unroll
    for (int ar = 0; ar < 4; ++ar) {
        float rs[4];
        #pragma unroll
        for (int reg = 0; reg < 4; ++reg) {
            float v = acc[ar][0][reg] + acc[ar][1][reg] + acc[ar][2][reg] + acc[ar][3][reg];
            v += __shfl_xor(v, 1); v += __shfl_xor(v, 2);
            v += __shfl_xor(v, 4); v += __shfl_xor(v, 8);
            rs[reg] = v;
        }
        if (cq == 0) {
            #pragma unroll
            for (int reg = 0; reg < 4; ++reg)
                atomicAdd(&rsum_lds[wr * 64 + ar * 16 + quad * 4 + reg], rs[reg]);
        }
    }

    // Col sums (symmetry): only for off-diagonal blocks.
    if (!diagblk) {
        #pragma unroll
        for (int bc = 0; bc < 4; ++bc) {
            float cs = 0.0f;
            #pragma unroll
            for (int ar = 0; ar < 4; ++ar)
                #pragma unroll
                for (int reg = 0; reg < 4; ++reg)
                    cs += acc[ar][bc][reg];
            cs += __shfl_xor(cs, 16); cs += __shfl_xor(cs, 32);
            if (quad == 0) atomicAdd(&csum_lds[wc * 64 + bc * 16 + cq], cs);
        }
    }

    __syncthreads();
    if (tid < BM) atomicAdd(&rowsum[rowbase + tid], rsum_lds[tid]);
    else if (!diagblk) atomicAdd(&rowsum[colbase + tid - BM], csum_lds[tid - BM]);
#undef STAGE
#undef COMPUTE
}

// Kernel 3: single block, 1024 threads (16 waves; L2-latency-bound).
// mean_r( log(rowsum[r]) - pos[r & (BHALF-1)] ).
__global__ __launch_bounds__(1024) void finalize_kernel(
    const float* __restrict__ rowsum, const float* __restrict__ pos_ws,
    float* __restrict__ out)
{
    __shared__ float red[16];
    float s = 0.0f;
    for (int r = threadIdx.x; r < N_TOT; r += 1024)
        s += __logf(rowsum[r]) - pos_ws[r & (BHALF - 1)];
    #pragma unroll
    for (int off = 1; off < 64; off <<= 1) s += __shfl_xor(s, off);
    int wave = threadIdx.x >> 6, lane = threadIdx.x & 63;
    if (lane == 0) red[wave] = s;
    __syncthreads();
    if (threadIdx.x < 64) {
        float v = (threadIdx.x < 16) ? red[threadIdx.x] : 0.0f;
        #pragma unroll
        for (int off = 1; off < 16; off <<= 1) v += __shfl_xor(v, off);
        if (threadIdx.x == 0) out[0] = v * (1.0f / N_TOT);
    }
}

extern "C" void kernel_launch(void* const* d_in, const int* in_sizes, int n_in,
                              void* d_out, int out_size, void* d_ws, size_t ws_size,
                              hipStream_t stream) {
    const float* zis = (const float*)d_in[0];
    const float* zjs = (const float*)d_in[1];
    float* rowsum = (float*)d_ws;                                   // 32 KB
    float* pos_ws = rowsum + N_TOT;                                 // 16 KB
    float* corr   = pos_ws + BHALF;                                 // 32 KB
    unsigned char* zq = (unsigned char*)(corr + N_TOT);             // 4 MB, 16B-aligned
    float* out = (float*)d_out;

    normalize_kernel<<<N_TOT / 4, 256, 0, stream>>>(zis, zjs, zq, corr, rowsum);
    ntxent_tri_kernel<<<NBLOCKS, 256, 0, stream>>>(zq, corr, rowsum, pos_ws);
    finalize_kernel<<<1, 1024, 0, stream>>>(rowsum, pos_ws, out);
}